// Round 3
// baseline (2692.026 us; speedup 1.0000x reference)
//
#include <hip/hip_runtime.h>
#include <math.h>

#define BB 4
#define CC 150
#define HH 320
#define WW 320
#define HW (HH*WW)      // 102400
#define KP 49

typedef unsigned int uint32;
typedef unsigned short u16;
typedef short bf16x8 __attribute__((ext_vector_type(8)));
typedef float f32x4 __attribute__((ext_vector_type(4)));
typedef uint32 u32x4 __attribute__((ext_vector_type(4)));

__device__ inline u16 f2bf(float x) {   // round-to-nearest-even
    union { float f; uint32 u; } v; v.f = x;
    uint32 r = v.u + 0x7FFFu + ((v.u >> 16) & 1u);
    return (u16)(r >> 16);
}
__device__ inline void unpk(uint32 d, float* w) {  // 2 packed bf16 -> 2 f32
    union { uint32 u; float f; } a, b;
    a.u = d << 16; b.u = d & 0xFFFF0000u;
    w[0] = a.f; w[1] = b.f;
}

// ---------------------------------------------------------------------------
// K0: compA[o*160 + k] = bf16(sigmoid(100*comp[o*150+k])), zero-padded 160x160
// ---------------------------------------------------------------------------
__global__ void k0_prep(const float* __restrict__ comp, u16* __restrict__ compA) {
    int idx = blockIdx.x * 256 + threadIdx.x;
    if (idx < 160 * 160) {
        int o = idx / 160;
        int k = idx - o * 160;
        float r = 0.f;
        if (o < CC && k < CC) {
            float v = comp[o * CC + k];
            r = 1.0f / (1.0f + __expf(-100.0f * v));
        }
        compA[idx] = f2bf(r);
    }
}

// ---------------------------------------------------------------------------
// K1: single-pass softmax + bf16 MFMA channel mix.  (unchanged this round;
// becomes the top profiled dispatch once k3 drops -> counters next round)
// ---------------------------------------------------------------------------
__global__ __launch_bounds__(256) void k1_softmax_mix(
    const float* __restrict__ logit, const u16* __restrict__ compA,
    u16* __restrict__ R)
{
    __shared__ __align__(16) u16 Qb[20][64][8];   // 20480 B, MFMA-B layout
    __shared__ float red[4][64];

    const int tid = threadIdx.x;
    const int p   = tid & 63;
    const int g   = tid >> 6;
    const int b   = blockIdx.y;
    const int pix0 = blockIdx.x * 64;

    const float* src = logit + (size_t)b * CC * HW + pix0 + p;

    float ev[38];
    float s = 0.f;
#pragma unroll
    for (int k = 0; k < 38; ++k) {
        int c = 38 * g + k;
        float e = 0.f;
        if (c < CC) e = __expf(src[(size_t)c * HW]);
        ev[k] = e;
        s += e;
    }
    red[g][p] = s;
    // zero pad rows c=150..159
    if (tid < 64) {
        *(uint32*)&Qb[18][tid][6] = 0u;
        *(u32x4*)&Qb[19][tid][0] = (u32x4){0u, 0u, 0u, 0u};
    }
    __syncthreads();
    const float inv = 1.0f / (red[0][p] + red[1][p] + red[2][p] + red[3][p]);
    // paired u32 LDS writes: c = 38g even always, pair (c, c+1) same Qb row
#pragma unroll
    for (int k = 0; k < 38; k += 2) {
        int c = 38 * g + k;
        if (c < CC) {
            uint32 w = (uint32)f2bf(ev[k] * inv)
                     | ((uint32)f2bf(ev[k + 1] * inv) << 16);
            *(uint32*)&Qb[c >> 3][p][c & 7] = w;
        }
    }
    __syncthreads();

    // MFMA: wave g owns pixels g*16..g*16+15
    const int n    = p & 15;
    const int quad = p >> 4;

    f32x4 acc[10];
#pragma unroll
    for (int mt = 0; mt < 10; ++mt) acc[mt] = (f32x4){0.f, 0.f, 0.f, 0.f};

#pragma unroll
    for (int ks = 0; ks < 5; ++ks) {
        bf16x8 bfrag = *(const bf16x8*)&Qb[ks * 4 + quad][g * 16 + n][0];
#pragma unroll
        for (int mt = 0; mt < 10; ++mt) {
            bf16x8 afrag = *(const bf16x8*)(compA + (mt * 16 + n) * 160
                                            + ks * 32 + quad * 8);
            acc[mt] = __builtin_amdgcn_mfma_f32_16x16x32_bf16(afrag, bfrag,
                                                              acc[mt], 0, 0, 0);
        }
    }

    // epilogue: transpose through LDS (reuse Qb space: 150*64 u16 = 19200 B)
    __syncthreads();                  // all Qb reads complete
    u16* S = &Qb[0][0][0];
#pragma unroll
    for (int mt = 0; mt < 10; ++mt) {
#pragma unroll
        for (int r = 0; r < 4; ++r) {
            int o = mt * 16 + quad * 4 + r;
            if (o < CC) S[o * 64 + g * 16 + n] = f2bf(acc[mt][r]);
        }
    }
    __syncthreads();
    u16* dstB = R + (size_t)b * CC * HW + pix0;
    for (int idx = tid; idx < CC * 8; idx += 256) {   // 1200 b128 tasks
        int o = idx >> 3, seg = idx & 7;
        *(u32x4*)(dstB + (size_t)o * HW + seg * 8) =
            *(const u32x4*)&S[o * 64 + seg * 8];
    }
}

// ---------------------------------------------------------------------------
// K3: out[b,o,i,j] = logit[b,o,i,j] - sum F[b,p,i,j]*R[b,o,i+di-3,j+dj-3]
// Tile 32x64, 256 thr: tx owns 8 j's SPLIT INTO TWO SEQUENTIAL 4-j PASSES.
// Why: single-pass needed acc48+F56+w16 -> VGPR=132, just past the measured
// 128-reg occupancy cliff (2 waves/SIMD -> latency-bound, VALUBusy 20%).
// Per-pass live state ~90 VGPR -> 4 waves/SIMD, 4 blocks/CU (LDS 33KB = cap).
// F bytes unchanged (each pass loads its own 16-B half of the 32-B window);
// LDS b128 reads x2 (cheap vs FMA). Numerics identical.
// XCD remap kept (neutral on time, free).  NO min-waves launch bound (round-1
// lesson: (256,4) collapsed allocator to 64 VGPR -> 2.1 GB spills).
// ---------------------------------------------------------------------------
#define HT 32
#define WT 64
#define OB 6
#define RROWS 38
#define RSTR 72                    // bf16 per row (144 B, 16B-aligned)
#define RPLANE (RROWS * RSTR)      // 2736 bf16

__global__ __launch_bounds__(256) void k3_crf(
    const float* __restrict__ F, const float* __restrict__ logit,
    const u16* __restrict__ R, float* __restrict__ out)
{
    __shared__ __align__(16) u16 Rs[OB * RPLANE];   // 32832 B

    const int tid = threadIdx.x;
    const int tx = tid & 7;
    const int ty = tid >> 3;

    // ---- XCD-bijective remap: lin = bx + 5*by + 50*bz, 0..4999 ----
    const uint32 lin  = blockIdx.x + 5u * blockIdx.y + 50u * blockIdx.z;
    const uint32 xcd  = lin & 7u;
    const uint32 sl   = lin >> 3;
    const uint32 tl   = sl / 25u;
    const uint32 chnk = sl - tl * 25u;
    const uint32 tile = xcd * 25u + tl;
    const int btx = (int)(tile % 5u);
    const uint32 t2 = tile / 5u;
    const int bty = (int)(t2 % 10u);
    const int b   = (int)(t2 / 10u);
    const int oc  = (int)chnk * OB;

    const int i0 = bty * HT;
    const int j0 = btx * WT;
    const int i  = i0 + ty;
    const int jb = j0 + tx * 8;

    const u16*   Rb = R     + (size_t)b * CC * HW;
    const float* Fb = F     + (size_t)b * KP * HW + (size_t)i * WW + jb;
    const float* Lb = logit + (size_t)b * CC * HW;
    float*       Ob = out   + (size_t)b * CC * HW;

    // stage OB bf16 halo planes: rows i0-3..i0+34, cols j0-4..j0+67 (pairs)
    for (int idx = tid; idx < OB * RROWS * 36; idx += 256) {
        int u   = idx / (RROWS * 36);
        int rem = idx - u * (RROWS * 36);
        int r   = rem / 36;
        int c2  = rem - r * 36;
        int gi  = i0 - 3 + r;
        int gj  = j0 - 4 + 2 * c2;
        uint32 v = 0u;
        if (gi >= 0 && gi < HH && gj >= 0 && gj < WW)
            v = *(const uint32*)(Rb + (size_t)(oc + u) * HW + gi * WW + gj);
        *(uint32*)&Rs[u * RPLANE + r * RSTR + 2 * c2] = v;
    }
    __syncthreads();

    // Two sequential 4-j passes; pass p covers output cols jb+4p .. jb+4p+3.
#pragma unroll 1
    for (int pass = 0; pass < 2; ++pass) {
        float acc[OB][4];
#pragma unroll
        for (int u = 0; u < OB; ++u)
#pragma unroll
            for (int q = 0; q < 4; ++q) acc[u][q] = 0.f;

        const float* Fp = Fb + pass * 4;

#pragma unroll
        for (int di = 0; di < 7; ++di) {
            f32x4 f[7];
#pragma unroll
            for (int dj = 0; dj < 7; ++dj)
                f[dj] = *(const f32x4*)(Fp + (size_t)(di * 7 + dj) * HW);
#pragma unroll
            for (int u = 0; u < OB; ++u) {
                const uint32* wp = (const uint32*)&Rs[u * RPLANE
                                     + (ty + di) * RSTR + tx * 8];
                u32x4 wa = *(const u32x4*)wp;
                u32x4 wb = *(const u32x4*)(wp + 4);
                // w[x] = R col (jb + 4*pass - 4 + x); all indices static.
                float w[12];
                if (pass == 0) {
                    unpk(wa.x, w + 0);  unpk(wa.y, w + 2);
                    unpk(wa.z, w + 4);  unpk(wa.w, w + 6);
                    unpk(wb.x, w + 8);  unpk(wb.y, w + 10);
                } else {
                    unpk(wa.z, w + 0);  unpk(wa.w, w + 2);
                    unpk(wb.x, w + 4);  unpk(wb.y, w + 6);
                    unpk(wb.z, w + 8);  unpk(wb.w, w + 10);
                }
#pragma unroll
                for (int dj = 0; dj < 7; ++dj) {
                    acc[u][0] = fmaf(f[dj].x, w[1 + 0 + dj], acc[u][0]);
                    acc[u][1] = fmaf(f[dj].y, w[1 + 1 + dj], acc[u][1]);
                    acc[u][2] = fmaf(f[dj].z, w[1 + 2 + dj], acc[u][2]);
                    acc[u][3] = fmaf(f[dj].w, w[1 + 3 + dj], acc[u][3]);
                }
            }
        }

#pragma unroll
        for (int u = 0; u < OB; ++u) {
            size_t off = (size_t)(oc + u) * HW + (size_t)i * WW + jb + pass * 4;
            f32x4 l = __builtin_nontemporal_load((const f32x4*)(Lb + off));
            f32x4 o;
            o.x = l.x - acc[u][0]; o.y = l.y - acc[u][1];
            o.z = l.z - acc[u][2]; o.w = l.w - acc[u][3];
            __builtin_nontemporal_store(o, (f32x4*)(Ob + off));
        }
    }
}

// ---------------------------------------------------------------------------
extern "C" void kernel_launch(void* const* d_in, const int* in_sizes, int n_in,
                              void* d_out, int out_size, void* d_ws, size_t ws_size,
                              hipStream_t stream)
{
    const float* dF = (const float*)d_in[0];  // [4,49,320,320]
    const float* dL = (const float*)d_in[1];  // [4,150,320,320]
    const float* dC = (const float*)d_in[2];  // [150,150,1,1]

    u16* compA = (u16*)d_ws;                       // 160*160*2 = 51200 B
    u16* R     = (u16*)((char*)d_ws + (1 << 16));  // 122.88 MB bf16
    float* o   = (float*)d_out;

    hipLaunchKernelGGL(k0_prep, dim3((160 * 160 + 255) / 256), dim3(256), 0,
                       stream, dC, compA);
    hipLaunchKernelGGL(k1_softmax_mix, dim3(HW / 64, BB), dim3(256), 0, stream,
                       dL, compA, R);
    hipLaunchKernelGGL(k3_crf, dim3(WW / WT, HH / HT, BB * 25), dim3(256), 0,
                       stream, dF, dL, R, o);
}

// Round 4
// 890.102 us; speedup vs baseline: 3.0244x; 3.0244x over previous
//
#include <hip/hip_runtime.h>
#include <math.h>

#define BB 4
#define CC 150
#define HH 320
#define WW 320
#define HW (HH*WW)      // 102400
#define KP 49

typedef unsigned int uint32;
typedef unsigned short u16;
typedef short bf16x8 __attribute__((ext_vector_type(8)));
typedef float f32x4 __attribute__((ext_vector_type(4)));
typedef uint32 u32x4 __attribute__((ext_vector_type(4)));

__device__ inline u16 f2bf(float x) {   // round-to-nearest-even
    union { float f; uint32 u; } v; v.f = x;
    uint32 r = v.u + 0x7FFFu + ((v.u >> 16) & 1u);
    return (u16)(r >> 16);
}
__device__ inline void unpk(uint32 d, float* w) {  // 2 packed bf16 -> 2 f32
    union { uint32 u; float f; } a, b;
    a.u = d << 16; b.u = d & 0xFFFF0000u;
    w[0] = a.f; w[1] = b.f;
}

// ---------------------------------------------------------------------------
// K0: compA[o*160 + k] = bf16(sigmoid(100*comp[o*150+k])), zero-padded 160x160
// ---------------------------------------------------------------------------
__global__ void k0_prep(const float* __restrict__ comp, u16* __restrict__ compA) {
    int idx = blockIdx.x * 256 + threadIdx.x;
    if (idx < 160 * 160) {
        int o = idx / 160;
        int k = idx - o * 160;
        float r = 0.f;
        if (o < CC && k < CC) {
            float v = comp[o * CC + k];
            r = 1.0f / (1.0f + __expf(-100.0f * v));
        }
        compA[idx] = f2bf(r);
    }
}

// ---------------------------------------------------------------------------
// K1: single-pass softmax + bf16 MFMA channel mix.  ROUND-0 VERSION RESTORED:
// the transpose-epilogue/paired-write variant measured ~35-40us SLOWER
// (total 1068 -> 1105 with k3 fixed at 588).
// ---------------------------------------------------------------------------
__global__ __launch_bounds__(256) void k1_softmax_mix(
    const float* __restrict__ logit, const u16* __restrict__ compA,
    u16* __restrict__ R)
{
    __shared__ __align__(16) u16 Qb[20][64][8];   // 20480 B, MFMA-B layout
    __shared__ float red[4][64];

    const int tid = threadIdx.x;
    const int p   = tid & 63;
    const int g   = tid >> 6;
    const int b   = blockIdx.y;
    const int pix0 = blockIdx.x * 64;

    const float* src = logit + (size_t)b * CC * HW + pix0 + p;

    float ev[38];
    float s = 0.f;
#pragma unroll
    for (int k = 0; k < 38; ++k) {
        int c = g + 4 * k;
        float e = 0.f;
        if (c < CC) e = __expf(src[(size_t)c * HW]);
        ev[k] = e;
        s += e;
    }
    red[g][p] = s;
    // zero pad rows c=150..159
    if (tid < 64) {
        *(uint32*)&Qb[18][tid][6] = 0u;
        *(u32x4*)&Qb[19][tid][0] = (u32x4){0u, 0u, 0u, 0u};
    }
    __syncthreads();
    const float inv = 1.0f / (red[0][p] + red[1][p] + red[2][p] + red[3][p]);
#pragma unroll
    for (int k = 0; k < 38; ++k) {
        int c = g + 4 * k;
        if (c < CC) Qb[c >> 3][p][c & 7] = f2bf(ev[k] * inv);
    }
    __syncthreads();

    // MFMA: wave g owns pixels g*16..g*16+15
    const int n    = p & 15;
    const int quad = p >> 4;

    f32x4 acc[10];
#pragma unroll
    for (int mt = 0; mt < 10; ++mt) acc[mt] = (f32x4){0.f, 0.f, 0.f, 0.f};

#pragma unroll
    for (int ks = 0; ks < 5; ++ks) {
        bf16x8 bfrag = *(const bf16x8*)&Qb[ks * 4 + quad][g * 16 + n][0];
#pragma unroll
        for (int mt = 0; mt < 10; ++mt) {
            bf16x8 afrag = *(const bf16x8*)(compA + (mt * 16 + n) * 160
                                            + ks * 32 + quad * 8);
            acc[mt] = __builtin_amdgcn_mfma_f32_16x16x32_bf16(afrag, bfrag,
                                                              acc[mt], 0, 0, 0);
        }
    }

    u16* dst = R + (size_t)b * CC * HW + pix0 + g * 16 + n;
#pragma unroll
    for (int mt = 0; mt < 10; ++mt) {
#pragma unroll
        for (int r = 0; r < 4; ++r) {
            int o = mt * 16 + quad * 4 + r;
            if (o < CC) dst[(size_t)o * HW] = f2bf(acc[mt][r]);
        }
    }
}

// ---------------------------------------------------------------------------
// K3: out[b,o,i,j] = logit[b,o,i,j] - sum F[b,p,i,j]*R[b,o,i+di-3,j+dj-3]
// ROUND-0 LOOP BODY (proven 132-VGPR no-spill codegen), with OB 6 -> 5:
// one fewer acc row (-8 VGPR) to get under the measured 128-reg occupancy
// cliff (129-256 VGPR = 2 waves/SIMD; <=128 = 4) WITHOUT restructuring.
// Round-1 lesson: launch_bounds min-waves -> allocator collapse, 2.1 GB spills.
// Round-3 lesson: two-pass body restructure -> scheduler hoist, VGPR 256.
// Grid z = 4 batches x 30 chunks; remap: 6000 blocks = 8 XCD x 25 tiles x 30.
// ---------------------------------------------------------------------------
#define HT 32
#define WT 64
#define OB 5
#define NCH 30                     // 150 / OB
#define RROWS 38
#define RSTR 72                    // bf16 per row (144 B, 16B-aligned)
#define RPLANE (RROWS * RSTR)      // 2736 bf16

__global__ __launch_bounds__(256) void k3_crf(
    const float* __restrict__ F, const float* __restrict__ logit,
    const u16* __restrict__ R, float* __restrict__ out)
{
    __shared__ __align__(16) u16 Rs[OB * RPLANE];   // 27360 B

    const int tid = threadIdx.x;
    const int tx = tid & 7;
    const int ty = tid >> 3;

    // ---- XCD-bijective remap: lin = bx + 5*by + 50*bz, 0..5999 ----
    const uint32 lin  = blockIdx.x + 5u * blockIdx.y + 50u * blockIdx.z;
    const uint32 xcd  = lin & 7u;          // 6000 = 8 * 750
    const uint32 sl   = lin >> 3;          // per-XCD slot, 0..749
    const uint32 tl   = sl / NCH;          // local tile 0..24
    const uint32 chnk = sl - tl * NCH;     // oc-chunk 0..29 (consecutive slots)
    const uint32 tile = xcd * 25u + tl;    // global tile 0..199
    const int btx = (int)(tile % 5u);
    const uint32 t2 = tile / 5u;
    const int bty = (int)(t2 % 10u);
    const int b   = (int)(t2 / 10u);
    const int oc  = (int)chnk * OB;

    const int i0 = bty * HT;
    const int j0 = btx * WT;
    const int i  = i0 + ty;
    const int jb = j0 + tx * 8;

    const u16*   Rb = R     + (size_t)b * CC * HW;
    const float* Fb = F     + (size_t)b * KP * HW + (size_t)i * WW + jb;
    const float* Lb = logit + (size_t)b * CC * HW;
    float*       Ob = out   + (size_t)b * CC * HW;

    // stage OB bf16 halo planes: rows i0-3..i0+34, cols j0-4..j0+67 (pairs)
    for (int idx = tid; idx < OB * RROWS * 36; idx += 256) {
        int u   = idx / (RROWS * 36);
        int rem = idx - u * (RROWS * 36);
        int r   = rem / 36;
        int c2  = rem - r * 36;
        int gi  = i0 - 3 + r;
        int gj  = j0 - 4 + 2 * c2;
        uint32 v = 0u;
        if (gi >= 0 && gi < HH && gj >= 0 && gj < WW)
            v = *(const uint32*)(Rb + (size_t)(oc + u) * HW + gi * WW + gj);
        *(uint32*)&Rs[u * RPLANE + r * RSTR + 2 * c2] = v;
    }
    __syncthreads();

    float acc[OB][8];
#pragma unroll
    for (int u = 0; u < OB; ++u)
#pragma unroll
        for (int q = 0; q < 8; ++q) acc[u][q] = 0.f;

#pragma unroll
    for (int di = 0; di < 7; ++di) {
        f32x4 fa[7], fb[7];
#pragma unroll
        for (int dj = 0; dj < 7; ++dj) {
            const float* fp = Fb + (size_t)(di * 7 + dj) * HW;
            fa[dj] = *(const f32x4*)(fp);
            fb[dj] = *(const f32x4*)(fp + 4);
        }
#pragma unroll
        for (int u = 0; u < OB; ++u) {
            const uint32* wp = (const uint32*)&Rs[u * RPLANE + (ty + di) * RSTR
                                                 + tx * 8];
            u32x4 wa = *(const u32x4*)wp;
            u32x4 wb = *(const u32x4*)(wp + 4);
            float w[16];
            unpk(wa.x, w + 0);  unpk(wa.y, w + 2);
            unpk(wa.z, w + 4);  unpk(wa.w, w + 6);
            unpk(wb.x, w + 8);  unpk(wb.y, w + 10);
            unpk(wb.z, w + 12); unpk(wb.w, w + 14);
#pragma unroll
            for (int dj = 0; dj < 7; ++dj) {
                acc[u][0] = fmaf(fa[dj].x, w[1 + 0 + dj], acc[u][0]);
                acc[u][1] = fmaf(fa[dj].y, w[1 + 1 + dj], acc[u][1]);
                acc[u][2] = fmaf(fa[dj].z, w[1 + 2 + dj], acc[u][2]);
                acc[u][3] = fmaf(fa[dj].w, w[1 + 3 + dj], acc[u][3]);
                acc[u][4] = fmaf(fb[dj].x, w[5 + 0 + dj], acc[u][4]);
                acc[u][5] = fmaf(fb[dj].y, w[5 + 1 + dj], acc[u][5]);
                acc[u][6] = fmaf(fb[dj].z, w[5 + 2 + dj], acc[u][6]);
                acc[u][7] = fmaf(fb[dj].w, w[5 + 3 + dj], acc[u][7]);
            }
        }
    }

#pragma unroll
    for (int u = 0; u < OB; ++u) {
        size_t off = (size_t)(oc + u) * HW + (size_t)i * WW + jb;
        f32x4 l0 = __builtin_nontemporal_load((const f32x4*)(Lb + off));
        f32x4 l1 = __builtin_nontemporal_load((const f32x4*)(Lb + off) + 1);
        f32x4 o0, o1;
        o0.x = l0.x - acc[u][0]; o0.y = l0.y - acc[u][1];
        o0.z = l0.z - acc[u][2]; o0.w = l0.w - acc[u][3];
        o1.x = l1.x - acc[u][4]; o1.y = l1.y - acc[u][5];
        o1.z = l1.z - acc[u][6]; o1.w = l1.w - acc[u][7];
        __builtin_nontemporal_store(o0, (f32x4*)(Ob + off));
        __builtin_nontemporal_store(o1, (f32x4*)(Ob + off) + 1);
    }
}

// ---------------------------------------------------------------------------
extern "C" void kernel_launch(void* const* d_in, const int* in_sizes, int n_in,
                              void* d_out, int out_size, void* d_ws, size_t ws_size,
                              hipStream_t stream)
{
    const float* dF = (const float*)d_in[0];  // [4,49,320,320]
    const float* dL = (const float*)d_in[1];  // [4,150,320,320]
    const float* dC = (const float*)d_in[2];  // [150,150,1,1]

    u16* compA = (u16*)d_ws;                       // 160*160*2 = 51200 B
    u16* R     = (u16*)((char*)d_ws + (1 << 16));  // 122.88 MB bf16
    float* o   = (float*)d_out;

    hipLaunchKernelGGL(k0_prep, dim3((160 * 160 + 255) / 256), dim3(256), 0,
                       stream, dC, compA);
    hipLaunchKernelGGL(k1_softmax_mix, dim3(HW / 64, BB), dim3(256), 0, stream,
                       dL, compA, R);
    hipLaunchKernelGGL(k3_crf, dim3(WW / WT, HH / HT, BB * NCH), dim3(256), 0,
                       stream, dF, dL, R, o);
}